// Round 2
// baseline (191.356 us; speedup 1.0000x reference)
//
#include <hip/hip_runtime.h>

// out[o,i,h,w] = sum_k weights[o,i,k] * x[k,h,w]
// weights: (2048, 2048, 3) fp32   x: (3, 3, 3) fp32   out: (2048, 2048, 3, 3) fp32
//
// Memory-bound: 50.3 MB read + 151 MB write, ~190 MFLOP. Target ~32 us @ 6.3 TB/s.
//
// V2b: 16B/lane everywhere (G13), using clang native vectors (f32x4) because
// __builtin_nontemporal_store rejects HIP_vector_type float4.
// Each thread owns 4 consecutive (o,i) pairs:
//   - loads 12 weight floats as 3 x f32x4 (48 B, aligned: 4 pairs * 3 floats * 4 B)
//   - computes 36 outputs in registers (fully unrolled, static indices -> no scratch)
//   - stages them as 9 x ds_write_b128 (lane stride = 9 float4s; odd stride gives an
//     even mod-8 bank-group distribution -> floor LDS throughput, no conflict penalty)
//   - cooperative flush: 9 fully-coalesced nontemporal 16B stores per thread
// Exact cover: 4096 blocks * 36864 B = 150,994,944 B = out size.

typedef float f32x4 __attribute__((ext_vector_type(4)));

#define THREADS 256
#define PAIRS_PER_THREAD 4
#define PAIRS_PER_BLOCK (THREADS * PAIRS_PER_THREAD)        // 1024
#define OUT_FLOATS_PER_BLOCK (PAIRS_PER_BLOCK * 9)          // 9216 floats = 36864 B

__global__ __launch_bounds__(THREADS) void gf_kernel(const float* __restrict__ x,
                                                     const float* __restrict__ w,
                                                     float* __restrict__ out) {
    __shared__ __align__(16) float so[OUT_FLOATS_PER_BLOCK];

    const int t = threadIdx.x;
    const size_t pairBase = (size_t)blockIdx.x * PAIRS_PER_BLOCK;

    // 12 contiguous weight floats per thread as 3 x f32x4.
    // Block's weight slab starts at w + pairBase*3 floats (12288 B, 16B-aligned).
    const f32x4* __restrict__ wv = (const f32x4*)(w + pairBase * 3);
    const f32x4 a = wv[t * 3 + 0];
    const f32x4 b = wv[t * 3 + 1];
    const f32x4 c = wv[t * 3 + 2];

    // x is 27 floats, wave-uniform; loads hoisted once, cache-served.
    float xv[27];
#pragma unroll
    for (int i = 0; i < 27; ++i) xv[i] = x[i];

    // Per-pair weight triples, unpacked from the three f32x4s (static indices).
    const float wq[4][3] = {{a.x, a.y, a.z},
                            {a.w, b.x, b.y},
                            {b.z, b.w, c.x},
                            {c.y, c.z, c.w}};

    // 36 outputs in registers, fully unrolled.
    float o[36];
#pragma unroll
    for (int q = 0; q < 4; ++q) {
#pragma unroll
        for (int hw = 0; hw < 9; ++hw) {
            o[q * 9 + hw] = wq[q][0] * xv[hw]
                          + wq[q][1] * xv[9 + hw]
                          + wq[q][2] * xv[18 + hw];
        }
    }

    // Stage to LDS: thread t owns f32x4-indices [9t, 9t+9) == its pairs' outputs.
    f32x4* __restrict__ sov = (f32x4*)so;
#pragma unroll
    for (int j = 0; j < 9; ++j) {
        f32x4 v = {o[4 * j + 0], o[4 * j + 1], o[4 * j + 2], o[4 * j + 3]};
        sov[t * 9 + j] = v;
    }

    __syncthreads();

    // Cooperative flush: 2304 f32x4s = 9 waves of 256, fully coalesced, 16B-aligned.
    // Nontemporal: output is write-once, never re-read -> don't retain in L2.
    f32x4* __restrict__ outv = (f32x4*)(out + pairBase * 9);
    const f32x4* __restrict__ s4 = (const f32x4*)so;
#pragma unroll
    for (int i = 0; i < 9; ++i) {
        __builtin_nontemporal_store(s4[t + THREADS * i], &outv[t + THREADS * i]);
    }
}

extern "C" void kernel_launch(void* const* d_in, const int* in_sizes, int n_in,
                              void* d_out, int out_size, void* d_ws, size_t ws_size,
                              hipStream_t stream) {
    const float* x = (const float*)d_in[0];   // 27 floats
    const float* w = (const float*)d_in[1];   // 2048*2048*3 floats
    float* out = (float*)d_out;               // 2048*2048*9 floats

    const int pairs = 2048 * 2048;                    // 4,194,304
    const int blocks = pairs / PAIRS_PER_BLOCK;       // 4096, exact cover
    gf_kernel<<<blocks, THREADS, 0, stream>>>(x, w, out);
}

// Round 3
// 189.433 us; speedup vs baseline: 1.0102x; 1.0102x over previous
//
#include <hip/hip_runtime.h>

// out[o,i,h,w] = sum_k weights[o,i,k] * x[k,h,w]
// weights: (2048, 2048, 3) fp32   x: (3, 3, 3) fp32   out: (2048, 2048, 3, 3) fp32
//
// Memory-bound: 50.3 MB read + 151 MB write, ~190 MFLOP. Target ~32 us @ 6.3 TB/s.
//
// V3: V2 structure, plain cached stores (NT store was the single suspect for the
// 185.5 -> 191.4 us regression; harness fills prove 6.7 TB/s through the cached
// write path). 16B/lane everywhere (G13). Each thread owns 4 consecutive (o,i)
// pairs:
//   - loads 12 weight floats as 3 x f32x4 (48 B, aligned: 4 pairs * 3 floats * 4 B)
//   - computes 36 outputs in registers (fully unrolled, static indices -> no scratch)
//   - stages them as 9 x ds_write_b128 (lane stride = 9 float4s ≡ 1 mod 8 bank
//     groups -> perfectly even distribution, floor LDS throughput)
//   - cooperative flush: 9 fully-coalesced 16B stores per thread
// Exact cover: 4096 blocks * 36864 B = 150,994,944 B = out size.

typedef float f32x4 __attribute__((ext_vector_type(4)));

#define THREADS 256
#define PAIRS_PER_THREAD 4
#define PAIRS_PER_BLOCK (THREADS * PAIRS_PER_THREAD)        // 1024
#define OUT_FLOATS_PER_BLOCK (PAIRS_PER_BLOCK * 9)          // 9216 floats = 36864 B

__global__ __launch_bounds__(THREADS) void gf_kernel(const float* __restrict__ x,
                                                     const float* __restrict__ w,
                                                     float* __restrict__ out) {
    __shared__ __align__(16) float so[OUT_FLOATS_PER_BLOCK];

    const int t = threadIdx.x;
    const size_t pairBase = (size_t)blockIdx.x * PAIRS_PER_BLOCK;

    // 12 contiguous weight floats per thread as 3 x f32x4.
    // Block's weight slab starts at w + pairBase*3 floats (12288 B, 16B-aligned).
    const f32x4* __restrict__ wv = (const f32x4*)(w + pairBase * 3);
    const f32x4 a = wv[t * 3 + 0];
    const f32x4 b = wv[t * 3 + 1];
    const f32x4 c = wv[t * 3 + 2];

    // x is 27 floats, wave-uniform; loads hoisted once, cache-served (s_load).
    float xv[27];
#pragma unroll
    for (int i = 0; i < 27; ++i) xv[i] = x[i];

    // Per-pair weight triples, unpacked from the three f32x4s (static indices).
    const float wq[4][3] = {{a.x, a.y, a.z},
                            {a.w, b.x, b.y},
                            {b.z, b.w, c.x},
                            {c.y, c.z, c.w}};

    // 36 outputs in registers, fully unrolled.
    float o[36];
#pragma unroll
    for (int q = 0; q < 4; ++q) {
#pragma unroll
        for (int hw = 0; hw < 9; ++hw) {
            o[q * 9 + hw] = wq[q][0] * xv[hw]
                          + wq[q][1] * xv[9 + hw]
                          + wq[q][2] * xv[18 + hw];
        }
    }

    // Stage to LDS: thread t owns f32x4-indices [9t, 9t+9) == its pairs' outputs.
    f32x4* __restrict__ sov = (f32x4*)so;
#pragma unroll
    for (int j = 0; j < 9; ++j) {
        f32x4 v = {o[4 * j + 0], o[4 * j + 1], o[4 * j + 2], o[4 * j + 3]};
        sov[t * 9 + j] = v;
    }

    __syncthreads();

    // Cooperative flush: 2304 f32x4s = 9 rounds of 256 lanes, fully coalesced,
    // 16B-aligned, through the normal cached write path (no NT).
    f32x4* __restrict__ outv = (f32x4*)(out + pairBase * 9);
    const f32x4* __restrict__ s4 = (const f32x4*)so;
#pragma unroll
    for (int i = 0; i < 9; ++i) {
        outv[t + THREADS * i] = s4[t + THREADS * i];
    }
}

extern "C" void kernel_launch(void* const* d_in, const int* in_sizes, int n_in,
                              void* d_out, int out_size, void* d_ws, size_t ws_size,
                              hipStream_t stream) {
    const float* x = (const float*)d_in[0];   // 27 floats
    const float* w = (const float*)d_in[1];   // 2048*2048*3 floats
    float* out = (float*)d_out;               // 2048*2048*9 floats

    const int pairs = 2048 * 2048;                    // 4,194,304
    const int blocks = pairs / PAIRS_PER_BLOCK;       // 4096, exact cover
    gf_kernel<<<blocks, THREADS, 0, stream>>>(x, w, out);
}

// Round 5
// 188.896 us; speedup vs baseline: 1.0130x; 1.0028x over previous
//
#include <hip/hip_runtime.h>

// out[o,i,h,w] = sum_k weights[o,i,k] * x[k,h,w]
// weights: (2048, 2048, 3) fp32   x: (3, 3, 3) fp32   out: (2048, 2048, 3, 3) fp32
//
// Memory-bound: 50.3 MB read + 151 MB write, ~190 MFLOP. Roofline ~32-38 us
// (202 MB @ 5.3-6.3 TB/s mixed). Harness timing has a fixed floor (poison fills
// dominate the profile; gf_kernel < 89.5 us in all profiled dispatches).
//
// V4: full occupancy. PPT=2 -> 18,432 B LDS/block -> 8 blocks/CU = 32 waves/CU
// (V3's 36 KB LDS capped us at 16 waves/CU; the read stream needs waves in
// flight to cover HBM latency, unlike the write-only harness fill which
// saturates at 9% occupancy). __launch_bounds__(256,8) caps VGPR at 64.
//   - per thread: 2 pairs, 6 weight floats as 3 x f32x2 (24 B, 8B-aligned,
//     wave-contiguous 1536 B)
//   - 18 outputs in registers (fully unrolled, static indices)
//   - stage as 9 x ds_write_b64: byte addr 72t+8j -> bank pair (18t+2j)%32,
//     every bank hit exactly 4x per instr = even, floor throughput
//   - flush: 1152 f32x4/block, 4 full coalesced rounds + 128-lane tail, cached
// Exact cover: 8192 blocks * 18,432 B = 150,994,944 B = out size.

typedef float f32x2 __attribute__((ext_vector_type(2)));
typedef float f32x4 __attribute__((ext_vector_type(4)));

#define THREADS 256
#define PPT 2
#define PAIRS_PER_BLOCK (THREADS * PPT)                 // 512
#define OUT_FLOATS_PER_BLOCK (PAIRS_PER_BLOCK * 9)      // 4608 floats = 18432 B
#define OUT_F4_PER_BLOCK (OUT_FLOATS_PER_BLOCK / 4)     // 1152

__global__ __launch_bounds__(THREADS, 8) void gf_kernel(const float* __restrict__ x,
                                                        const float* __restrict__ w,
                                                        float* __restrict__ out) {
    __shared__ __align__(16) float so[OUT_FLOATS_PER_BLOCK];

    const int t = threadIdx.x;
    const size_t g = (size_t)blockIdx.x * THREADS + t;  // global thread id

    // 6 contiguous weight floats per thread as 3 x f32x2 (8B-aligned: 24 B * g).
    const f32x2* __restrict__ wv = (const f32x2*)(w + g * 6);
    const f32x2 l0 = wv[0];
    const f32x2 l1 = wv[1];
    const f32x2 l2 = wv[2];

    // x is 27 floats, wave-uniform -> scalar loads, cache-served.
    float xv[27];
#pragma unroll
    for (int i = 0; i < 27; ++i) xv[i] = x[i];

    // Pair A weights: (l0.x, l0.y, l1.x); pair B: (l1.y, l2.x, l2.y).
    float o[18];
#pragma unroll
    for (int hw = 0; hw < 9; ++hw) {
        o[hw]     = l0.x * xv[hw] + l0.y * xv[9 + hw] + l1.x * xv[18 + hw];
        o[9 + hw] = l1.y * xv[hw] + l2.x * xv[9 + hw] + l2.y * xv[18 + hw];
    }

    // Stage: thread t owns f32x2-slots [9t, 9t+9) == floats [18t, 18t+18).
    f32x2* __restrict__ sov = (f32x2*)so;
#pragma unroll
    for (int j = 0; j < 9; ++j) {
        f32x2 v = {o[2 * j], o[2 * j + 1]};
        sov[t * 9 + j] = v;
    }

    __syncthreads();

    // Flush: 1152 f32x4 = 4 full rounds of 256 + 128-lane tail; fully coalesced,
    // 16B-aligned, cached write path.
    f32x4* __restrict__ outv = (f32x4*)(out + (size_t)blockIdx.x * OUT_FLOATS_PER_BLOCK);
    const f32x4* __restrict__ s4 = (const f32x4*)so;
#pragma unroll
    for (int i = 0; i < 4; ++i) {
        outv[t + THREADS * i] = s4[t + THREADS * i];
    }
    if (t < OUT_F4_PER_BLOCK - 4 * THREADS) {           // 128 remainder slots
        outv[t + 4 * THREADS] = s4[t + 4 * THREADS];
    }
}

extern "C" void kernel_launch(void* const* d_in, const int* in_sizes, int n_in,
                              void* d_out, int out_size, void* d_ws, size_t ws_size,
                              hipStream_t stream) {
    const float* x = (const float*)d_in[0];   // 27 floats
    const float* w = (const float*)d_in[1];   // 2048*2048*3 floats
    float* out = (float*)d_out;               // 2048*2048*9 floats

    const int pairs = 2048 * 2048;                    // 4,194,304
    const int blocks = pairs / PAIRS_PER_BLOCK;       // 8192, exact cover
    gf_kernel<<<blocks, THREADS, 0, stream>>>(x, w, out);
}